// Round 5
// baseline (1814.586 us; speedup 1.0000x reference)
//
#include <hip/hip_runtime.h>
#include <hip/hip_fp16.h>

// Problem constants
#define BB 128
#define SS 512
#define EE 16
#define HH 256
#define G3 768
#define VV 256

typedef _Float16 half8 __attribute__((ext_vector_type(8)));
typedef _Float16 half4_t __attribute__((ext_vector_type(4)));
typedef float f32x4 __attribute__((ext_vector_type(4)));

// ---------------------------------------------------------------------------
// P: swizzle W_hh [256][768] and W_out [256][256] (fp32, row=K, col=N) into
// fp16 MFMA B-fragment order: flat idx = ((n_tile*8 + k_tile)*64 + lane)*8 + j
//   = n*4096 + k*512 + L*8 + j
// holding W[k_tile*32 + (lane>>4)*8 + j][n_tile*16 + (lane&15)].
// DECODE: j=bits0-2, L=bits3-8, k=bits9-11, n=bits12+   (R1-R4 bug: k/n were
// taken from bits 6-8/9+, inside L's field -> scrambled weights, absmax 1.49)
// ---------------------------------------------------------------------------
__global__ __launch_bounds__(256) void swizzle_weights(
    const float* __restrict__ Whh, const float* __restrict__ Wout,
    _Float16* __restrict__ whh_swz, _Float16* __restrict__ wout_swz) {
  int t = blockIdx.x * 256 + threadIdx.x;
  if (t < 48 * 8 * 64 * 8) {  // 196608 elements of W_hh
    int j = t & 7, L = (t >> 3) & 63, k = (t >> 9) & 7, n = t >> 12;
    int row = k * 32 + (L >> 4) * 8 + j;
    int col = n * 16 + (L & 15);
    whh_swz[t] = (_Float16)Whh[row * G3 + col];
  }
  if (t < 16 * 8 * 64 * 8) {  // 65536 elements of W_out
    int j = t & 7, L = (t >> 3) & 63, k = (t >> 9) & 7, n = t >> 12;
    int row = k * 32 + (L >> 4) * 8 + j;
    int col = n * 16 + (L & 15);
    wout_swz[t] = (_Float16)Wout[row * VV + col];
  }
}

// ---------------------------------------------------------------------------
// K1: gi = emb[x] @ W_ih + b_ih (+ b_hh folded for r,z gates), written fp16 in
// the swizzled per-(batch-group, t) layout K2's lanes read with 8B loads:
//   group = (b>>4)*512 + t  (16 batch rows per group, 12288 fp16 per group)
//   slot  = ((g*16 + wi)*64 + q*16 + c)*4 + r
//   value = gi[row m=q*4+r][gatecol g*256 + wi*16 + c]
// Static LDS = 48 + 3 + 1 KB = 52 KB
// ---------------------------------------------------------------------------
__global__ __launch_bounds__(256) void gi_kernel(
    const int* __restrict__ x, const float* __restrict__ embed,
    const float* __restrict__ W_ih, const float* __restrict__ b_ih,
    const float* __restrict__ b_hh, _Float16* __restrict__ gi_swz) {
  int gid = blockIdx.x;  // 0..4095 = bg*512 + t
  int bg = gid >> 9, t = gid & 511;
  int tid = threadIdx.x;

  __shared__ __align__(16) float s_wih[EE * G3];    // 48 KB
  __shared__ __align__(16) float s_bias[G3];        // 3 KB
  __shared__ __align__(16) float s_emb16[16][EE];   // 1 KB
  __shared__ int s_x[16];

  for (int i = tid; i < EE * G3; i += 256) s_wih[i] = W_ih[i];
  for (int i = tid; i < G3; i += 256)
    s_bias[i] = b_ih[i] + (i < 512 ? b_hh[i] : 0.0f);  // fold b_hh for r,z only
  if (tid < 16) s_x[tid] = x[(bg * 16 + tid) * SS + t];
  __syncthreads();
  {  // stage this block's 16 embedding rows (1 value per thread)
    int m = tid >> 4, e = tid & 15;
    s_emb16[m][e] = embed[s_x[m] * EE + e];
  }
  __syncthreads();

  size_t gbase = (size_t)gid * (16 * G3);
  for (int cch = 0; cch < 3; cch++) {
    int gc = cch * 256 + tid;          // gate column
    float w[EE];
#pragma unroll
    for (int e = 0; e < EE; e++) w[e] = s_wih[e * G3 + gc];
    float bias = s_bias[gc];
    int wi = (gc >> 4) & 15, cc = gc & 15;
    int tilebase = (cch * 16 + wi) * 64;
#pragma unroll
    for (int m = 0; m < 16; m++) {
      float acc = bias;
#pragma unroll
      for (int e = 0; e < EE; e++) acc += s_emb16[m][e] * w[e];
      gi_swz[gbase + (size_t)((tilebase + (m >> 2) * 16 + cc) * 4 + (m & 3))] = (_Float16)acc;
    }
  }
}

// ---------------------------------------------------------------------------
// K2: GRU recurrence. 8 blocks x 1024 threads (16 waves); block bg owns batch
// rows [bg*16, bg*16+16). Wave w owns h-columns [w*16, w*16+16): exactly one
// N-tile per gate (r,z,n), so ALL of W_hh lives in VGPRs (3x8 half8 = 96 regs
// per lane) and the only LDS is the double-buffered fp16 h tile (16.9 KB).
// h: fp32 master in registers (4/lane), fp16 copy in LDS for MFMA A-reads.
// ---------------------------------------------------------------------------
__global__ __launch_bounds__(1024, 2) void gru_kernel(
    const _Float16* __restrict__ gi_swz, const _Float16* __restrict__ whh_swz,
    const float* __restrict__ b_hh, _Float16* __restrict__ h_seq) {
  int bg = blockIdx.x;  // 0..7
  int tid = threadIdx.x;
  int w = tid >> 6, L = tid & 63;
  int q = L >> 4, c = L & 15;

  __shared__ __align__(16) _Float16 s_h[2][16][264];  // 16.9 KB

  // All three B fragments for this wave's column tile, in registers.
  half8 wR[8], wZ[8], wN[8];
#pragma unroll
  for (int k = 0; k < 8; k++) {
    wR[k] = *(const half8*)(whh_swz + (((size_t)((0 * 16 + w) * 8 + k) * 64 + L) * 8));
    wZ[k] = *(const half8*)(whh_swz + (((size_t)((1 * 16 + w) * 8 + k) * 64 + L) * 8));
    wN[k] = *(const half8*)(whh_swz + (((size_t)((2 * 16 + w) * 8 + k) * 64 + L) * 8));
  }
  // n-gate hidden bias (multiplied by r inside the step)
  float bhn = b_hh[512 + w * 16 + c];

  // zero both h buffers (h0 = 0): 8448 halves = 4224 uints
  for (int idx = tid; idx < (2 * 16 * 264) / 2; idx += 1024)
    ((unsigned int*)s_h)[idx] = 0u;
  float hm[4] = {0.f, 0.f, 0.f, 0.f};
  __syncthreads();

  int cur = 0;
#pragma unroll 1
  for (int t = 0; t < SS; t++) {
    // gate-input loads (issued early, consumed in epilogue)
    size_t gbase = ((size_t)(bg * 512 + t)) * 12288;
    half4_t giR = *(const half4_t*)(gi_swz + gbase + (size_t)((0 * 16 + w) * 64 + L) * 4);
    half4_t giZ = *(const half4_t*)(gi_swz + gbase + (size_t)((1 * 16 + w) * 64 + L) * 4);
    half4_t giN = *(const half4_t*)(gi_swz + gbase + (size_t)((2 * 16 + w) * 64 + L) * 4);

    f32x4 aR = {0.f, 0.f, 0.f, 0.f}, aZ = aR, aN = aR;
    const _Float16* hsrc = &s_h[cur][0][0];
#pragma unroll
    for (int k = 0; k < 8; k++) {
      half8 av = *(const half8*)(hsrc + c * 264 + k * 32 + q * 8);  // A[m=c][k*32+q*8+j]
      aR = __builtin_amdgcn_mfma_f32_16x16x32_f16(av, wR[k], aR, 0, 0, 0);
      aZ = __builtin_amdgcn_mfma_f32_16x16x32_f16(av, wZ[k], aZ, 0, 0, 0);
      aN = __builtin_amdgcn_mfma_f32_16x16x32_f16(av, wN[k], aN, 0, 0, 0);
    }

    _Float16* hdst = &s_h[cur ^ 1][0][0];
    int col = w * 16 + c;
#pragma unroll
    for (int r = 0; r < 4; r++) {
      int m = q * 4 + r;  // C/D row = (lane>>4)*4 + reg
      float rg = aR[r] + (float)giR[r];
      rg = 1.f / (1.f + __expf(-rg));
      float zg = aZ[r] + (float)giZ[r];
      zg = 1.f / (1.f + __expf(-zg));
      float ng = (float)giN[r] + rg * (aN[r] + bhn);
      ng = 2.f / (1.f + __expf(-2.f * ng)) - 1.f;  // tanh
      float hn = (1.f - zg) * ng + zg * hm[r];
      hm[r] = hn;
      hdst[m * 264 + col] = (_Float16)hn;
      h_seq[((size_t)(bg * 16 + m) * SS + t) * HH + col] = (_Float16)hn;
    }
    __syncthreads();
    cur ^= 1;
  }
}

// ---------------------------------------------------------------------------
// K3: out = h_seq @ W_out + b_out via fp16 MFMA. 1024 blocks x 256 threads;
// block handles 64 bt-rows (wave w -> rows w*16..+16), full N=256 (16 tiles).
// Static LDS = 33 KB.  Output written fp32.
// ---------------------------------------------------------------------------
__global__ __launch_bounds__(256) void out_kernel(
    const _Float16* __restrict__ h_seq, const _Float16* __restrict__ wout_swz,
    const float* __restrict__ b_out, float* __restrict__ out) {
  int blk = blockIdx.x;
  int tid = threadIdx.x;
  int w = tid >> 6, L = tid & 63, q = L >> 4, c = L & 15;

  __shared__ __align__(16) _Float16 s_a[64 * 264];  // 33 KB

  const _Float16* src = h_seq + (size_t)blk * 64 * 256;
  for (int idx = tid; idx < (64 * 256) / 8; idx += 256) {
    int row = idx >> 5, kk = (idx & 31) * 8;
    *(half8*)(s_a + row * 264 + kk) = *(const half8*)(src + row * 256 + kk);
  }
  __syncthreads();

  half8 a[8];
#pragma unroll
  for (int k = 0; k < 8; k++)
    a[k] = *(const half8*)(s_a + (w * 16 + c) * 264 + k * 32 + q * 8);

  f32x4 acc[16];
#pragma unroll
  for (int n = 0; n < 16; n++) {
    f32x4 z = {0.f, 0.f, 0.f, 0.f};
    acc[n] = z;
#pragma unroll
    for (int k = 0; k < 8; k++) {
      half8 b = *(const half8*)(wout_swz + ((size_t)(n * 8 + k) * 64 + L) * 8);
      acc[n] = __builtin_amdgcn_mfma_f32_16x16x32_f16(a[k], b, acc[n], 0, 0, 0);
    }
  }
#pragma unroll
  for (int n = 0; n < 16; n++) {
    int v = n * 16 + c;
    float bo = b_out[v];
#pragma unroll
    for (int r = 0; r < 4; r++) {
      int bt = blk * 64 + w * 16 + q * 4 + r;
      out[(size_t)bt * 256 + v] = acc[n][r] + bo;
    }
  }
}

// ---------------------------------------------------------------------------
extern "C" void kernel_launch(void* const* d_in, const int* in_sizes, int n_in,
                              void* d_out, int out_size, void* d_ws, size_t ws_size,
                              hipStream_t stream) {
  const int*   x    = (const int*)d_in[0];
  const float* emb  = (const float*)d_in[1];
  const float* Wih  = (const float*)d_in[2];
  const float* bih  = (const float*)d_in[3];
  const float* Whh  = (const float*)d_in[4];
  const float* bhh  = (const float*)d_in[5];
  const float* Wout = (const float*)d_in[6];
  const float* bout = (const float*)d_in[7];

  char* ws = (char*)d_ws;
  // ws layout (134,742,016 B total):
  //   gi_swz   : 128*512*768 fp16 = 100,663,296 B
  //   whh_swz  : 196608 fp16      =     393,216 B
  //   wout_swz : 65536 fp16       =     131,072 B
  //   h_seq    : 128*512*256 fp16 =  33,554,432 B
  _Float16* gi_swz   = (_Float16*)(ws);
  _Float16* whh_swz  = (_Float16*)(ws + 100663296);
  _Float16* wout_swz = (_Float16*)(ws + 100663296 + 393216);
  _Float16* h_seq    = (_Float16*)(ws + 100663296 + 393216 + 131072);

  swizzle_weights<<<768, 256, 0, stream>>>(Whh, Wout, whh_swz, wout_swz);
  gi_kernel<<<4096, 256, 0, stream>>>(x, emb, Wih, bih, bhh, gi_swz);
  gru_kernel<<<8, 1024, 0, stream>>>(gi_swz, whh_swz, bhh, h_seq);
  out_kernel<<<1024, 256, 0, stream>>>(h_seq, wout_swz, bout, (float*)d_out);
}

// Round 6
// 1777.401 us; speedup vs baseline: 1.0209x; 1.0209x over previous
//
#include <hip/hip_runtime.h>
#include <hip/hip_fp16.h>

// Problem constants
#define BB 128
#define SS 512
#define EE 16
#define HH 256
#define G3 768
#define VV 256

typedef _Float16 half8 __attribute__((ext_vector_type(8)));
typedef _Float16 half4_t __attribute__((ext_vector_type(4)));
typedef float f32x4 __attribute__((ext_vector_type(4)));

// ---------------------------------------------------------------------------
// P: swizzle W_hh [256][768] and W_out [256][256] (fp32, row=K, col=N) into
// fp16 MFMA B-fragment order: flat idx = ((n_tile*8 + k_tile)*64 + lane)*8 + j
//   = n*4096 + k*512 + L*8 + j
// holding W[k_tile*32 + (lane>>4)*8 + j][n_tile*16 + (lane&15)].
// ---------------------------------------------------------------------------
__global__ __launch_bounds__(256) void swizzle_weights(
    const float* __restrict__ Whh, const float* __restrict__ Wout,
    _Float16* __restrict__ whh_swz, _Float16* __restrict__ wout_swz) {
  int t = blockIdx.x * 256 + threadIdx.x;
  if (t < 48 * 8 * 64 * 8) {  // 196608 elements of W_hh
    int j = t & 7, L = (t >> 3) & 63, k = (t >> 9) & 7, n = t >> 12;
    int row = k * 32 + (L >> 4) * 8 + j;
    int col = n * 16 + (L & 15);
    whh_swz[t] = (_Float16)Whh[row * G3 + col];
  }
  if (t < 16 * 8 * 64 * 8) {  // 65536 elements of W_out
    int j = t & 7, L = (t >> 3) & 63, k = (t >> 9) & 7, n = t >> 12;
    int row = k * 32 + (L >> 4) * 8 + j;
    int col = n * 16 + (L & 15);
    wout_swz[t] = (_Float16)Wout[row * VV + col];
  }
}

// ---------------------------------------------------------------------------
// K1: gi = emb[x] @ W_ih + b_ih (+ b_hh folded for r,z gates), written fp16 in
// the swizzled per-(batch-group, t) layout K2's lanes read with 8B loads.
// 1024 blocks; each block handles 4 timesteps for one batch group, amortizing
// the 48 KB W_ih LDS staging 4x.  Static LDS = 48 + 3 + 4 KB = 55 KB.
// ---------------------------------------------------------------------------
__global__ __launch_bounds__(256) void gi_kernel(
    const int* __restrict__ x, const float* __restrict__ embed,
    const float* __restrict__ W_ih, const float* __restrict__ b_ih,
    const float* __restrict__ b_hh, _Float16* __restrict__ gi_swz) {
  int gid = blockIdx.x;          // 0..1023
  int bg = gid >> 7;             // batch group 0..7
  int t0 = (gid & 127) * 4;      // 4 timesteps per block
  int tid = threadIdx.x;

  __shared__ __align__(16) float s_wih[EE * G3];      // 48 KB
  __shared__ __align__(16) float s_bias[G3];          // 3 KB
  __shared__ __align__(16) float s_emb16[4][16][EE];  // 4 KB
  __shared__ int s_x[4][16];

  for (int i = tid; i < EE * G3; i += 256) s_wih[i] = W_ih[i];
  for (int i = tid; i < G3; i += 256)
    s_bias[i] = b_ih[i] + (i < 512 ? b_hh[i] : 0.0f);  // fold b_hh for r,z only
  if (tid < 64) {
    int tt = tid >> 4, m = tid & 15;
    s_x[tt][m] = x[(bg * 16 + m) * SS + t0 + tt];
  }
  __syncthreads();
  for (int i = tid; i < 4 * 16 * EE; i += 256) {
    int tt = i >> 8, m = (i >> 4) & 15, e = i & 15;
    s_emb16[tt][m][e] = embed[s_x[tt][m] * EE + e];
  }
  __syncthreads();

  for (int cch = 0; cch < 3; cch++) {
    int gc = cch * 256 + tid;  // gate column
    float w[EE];
#pragma unroll
    for (int e = 0; e < EE; e++) w[e] = s_wih[e * G3 + gc];
    float bias = s_bias[gc];
    int wi = (gc >> 4) & 15, cc = gc & 15;
    int tilebase = (cch * 16 + wi) * 64;
    for (int tt = 0; tt < 4; tt++) {
      size_t gbase = (size_t)(bg * 512 + t0 + tt) * 12288;
#pragma unroll
      for (int mq = 0; mq < 4; mq++) {
        half4_t v;
#pragma unroll
        for (int r = 0; r < 4; r++) {
          int m = mq * 4 + r;
          float acc = bias;
#pragma unroll
          for (int e = 0; e < EE; e++) acc += s_emb16[tt][m][e] * w[e];
          v[r] = (_Float16)acc;
        }
        *(half4_t*)(gi_swz + gbase + (size_t)((tilebase + mq * 16 + cc) * 4)) = v;
      }
    }
  }
}

// ---------------------------------------------------------------------------
// K2: GRU recurrence. 8 blocks x 1024 threads (16 waves); block bg owns batch
// rows [bg*16, bg*16+16). Wave w owns h-columns [w*16, w*16+16): one N-tile
// per gate, so all of W_hh lives in VGPRs (3x8 half8 = 96 regs/lane).
// __launch_bounds__(1024, 4): 1 block/CU, 4 waves/SIMD, 128-VGPR budget --
// R5 had (1024,2) -> 64-VGPR cap -> weight arrays spilled to scratch
// (FETCH_SIZE 51 GB, 1590 us). h kept ONLY as fp16 in the double-buffered LDS
// tile (no fp32 master: saves 4 VGPRs; lane re-reads its own h_{t-1} as fp16).
// Static LDS = 16.9 KB.
// ---------------------------------------------------------------------------
__global__ __launch_bounds__(1024, 4) void gru_kernel(
    const _Float16* __restrict__ gi_swz, const _Float16* __restrict__ whh_swz,
    const float* __restrict__ b_hh, _Float16* __restrict__ h_seq) {
  int bg = blockIdx.x;  // 0..7
  int tid = threadIdx.x;
  int w = tid >> 6, L = tid & 63;
  int q = L >> 4, c = L & 15;

  __shared__ __align__(16) _Float16 s_h[2][16][264];  // 16.9 KB

  // All three B fragments for this wave's column tile, in registers (96 VGPR).
  half8 wR[8], wZ[8], wN[8];
#pragma unroll
  for (int k = 0; k < 8; k++) {
    wR[k] = *(const half8*)(whh_swz + (((size_t)((0 * 16 + w) * 8 + k) * 64 + L) * 8));
    wZ[k] = *(const half8*)(whh_swz + (((size_t)((1 * 16 + w) * 8 + k) * 64 + L) * 8));
    wN[k] = *(const half8*)(whh_swz + (((size_t)((2 * 16 + w) * 8 + k) * 64 + L) * 8));
  }
  // n-gate hidden bias (multiplied by r inside the step)
  float bhn = b_hh[512 + w * 16 + c];

  // zero both h buffers (h0 = 0): 8448 halves = 4224 uints
  for (int idx = tid; idx < (2 * 16 * 264) / 2; idx += 1024)
    ((unsigned int*)s_h)[idx] = 0u;
  __syncthreads();

  int col = w * 16 + c;
  // h_seq flat offset for (batch row bg*16 + q*4, t=0, col); advance by HH/step
  unsigned hoff = (unsigned)(bg * 16 + q * 4) * (SS * HH) + (unsigned)col;
  // gi base offset for this lane (advance by 12288/step)
  unsigned gioff = (unsigned)(bg * 512) * 12288u + (unsigned)((w * 64 + L) * 4);

  int cur = 0;
#pragma unroll 1
  for (int t = 0; t < SS; t++) {
    // gate-input loads (global; issued early, consumed in epilogue)
    half4_t giR = *(const half4_t*)(gi_swz + gioff);
    half4_t giZ = *(const half4_t*)(gi_swz + gioff + 4096u);
    half4_t giN = *(const half4_t*)(gi_swz + gioff + 8192u);

    const _Float16* hsrc = &s_h[cur][0][0];
    // lane's own h_{t-1} values (C-layout positions), fp16
    half4_t hp;
#pragma unroll
    for (int r = 0; r < 4; r++) hp[r] = hsrc[(q * 4 + r) * 264 + col];

    f32x4 aR = {0.f, 0.f, 0.f, 0.f}, aZ = aR, aN = aR;
#pragma unroll
    for (int k = 0; k < 8; k++) {
      half8 av = *(const half8*)(hsrc + c * 264 + k * 32 + q * 8);  // A[m=c][k*32+q*8+j]
      aR = __builtin_amdgcn_mfma_f32_16x16x32_f16(av, wR[k], aR, 0, 0, 0);
      aZ = __builtin_amdgcn_mfma_f32_16x16x32_f16(av, wZ[k], aZ, 0, 0, 0);
      aN = __builtin_amdgcn_mfma_f32_16x16x32_f16(av, wN[k], aN, 0, 0, 0);
    }

    _Float16* hdst = &s_h[cur ^ 1][0][0];
#pragma unroll
    for (int r = 0; r < 4; r++) {
      int m = q * 4 + r;  // C/D row = (lane>>4)*4 + reg
      float rg = aR[r] + (float)giR[r];
      rg = 1.f / (1.f + __expf(-rg));
      float zg = aZ[r] + (float)giZ[r];
      zg = 1.f / (1.f + __expf(-zg));
      float ng = (float)giN[r] + rg * (aN[r] + bhn);
      ng = 2.f / (1.f + __expf(-2.f * ng)) - 1.f;  // tanh
      float hn = (1.f - zg) * ng + zg * (float)hp[r];
      hdst[m * 264 + col] = (_Float16)hn;
      h_seq[(size_t)hoff + (unsigned)r * (SS * HH)] = (_Float16)hn;
    }
    __syncthreads();
    cur ^= 1;
    hoff += HH;
    gioff += 12288u;
  }
}

// ---------------------------------------------------------------------------
// K3: out = h_seq @ W_out + b_out via fp16 MFMA. 1024 blocks x 256 threads;
// block handles 64 bt-rows (wave w -> rows w*16..+16), full N=256 (16 tiles).
// Static LDS = 33 KB.  Output written fp32.
// ---------------------------------------------------------------------------
__global__ __launch_bounds__(256) void out_kernel(
    const _Float16* __restrict__ h_seq, const _Float16* __restrict__ wout_swz,
    const float* __restrict__ b_out, float* __restrict__ out) {
  int blk = blockIdx.x;
  int tid = threadIdx.x;
  int w = tid >> 6, L = tid & 63, q = L >> 4, c = L & 15;

  __shared__ __align__(16) _Float16 s_a[64 * 264];  // 33 KB

  const _Float16* src = h_seq + (size_t)blk * 64 * 256;
  for (int idx = tid; idx < (64 * 256) / 8; idx += 256) {
    int row = idx >> 5, kk = (idx & 31) * 8;
    *(half8*)(s_a + row * 264 + kk) = *(const half8*)(src + row * 256 + kk);
  }
  __syncthreads();

  half8 a[8];
#pragma unroll
  for (int k = 0; k < 8; k++)
    a[k] = *(const half8*)(s_a + (w * 16 + c) * 264 + k * 32 + q * 8);

  f32x4 acc[16];
#pragma unroll
  for (int n = 0; n < 16; n++) {
    f32x4 z = {0.f, 0.f, 0.f, 0.f};
    acc[n] = z;
#pragma unroll
    for (int k = 0; k < 8; k++) {
      half8 b = *(const half8*)(wout_swz + ((size_t)(n * 8 + k) * 64 + L) * 8);
      acc[n] = __builtin_amdgcn_mfma_f32_16x16x32_f16(a[k], b, acc[n], 0, 0, 0);
    }
  }
#pragma unroll
  for (int n = 0; n < 16; n++) {
    int v = n * 16 + c;
    float bo = b_out[v];
#pragma unroll
    for (int r = 0; r < 4; r++) {
      int bt = blk * 64 + w * 16 + q * 4 + r;
      out[(size_t)bt * 256 + v] = acc[n][r] + bo;
    }
  }
}

// ---------------------------------------------------------------------------
extern "C" void kernel_launch(void* const* d_in, const int* in_sizes, int n_in,
                              void* d_out, int out_size, void* d_ws, size_t ws_size,
                              hipStream_t stream) {
  const int*   x    = (const int*)d_in[0];
  const float* emb  = (const float*)d_in[1];
  const float* Wih  = (const float*)d_in[2];
  const float* bih  = (const float*)d_in[3];
  const float* Whh  = (const float*)d_in[4];
  const float* bhh  = (const float*)d_in[5];
  const float* Wout = (const float*)d_in[6];
  const float* bout = (const float*)d_in[7];

  char* ws = (char*)d_ws;
  // ws layout (134,742,016 B total):
  //   gi_swz   : 128*512*768 fp16 = 100,663,296 B
  //   whh_swz  : 196608 fp16      =     393,216 B
  //   wout_swz : 65536 fp16       =     131,072 B
  //   h_seq    : 128*512*256 fp16 =  33,554,432 B
  _Float16* gi_swz   = (_Float16*)(ws);
  _Float16* whh_swz  = (_Float16*)(ws + 100663296);
  _Float16* wout_swz = (_Float16*)(ws + 100663296 + 393216);
  _Float16* h_seq    = (_Float16*)(ws + 100663296 + 393216 + 131072);

  swizzle_weights<<<768, 256, 0, stream>>>(Whh, Wout, whh_swz, wout_swz);
  gi_kernel<<<1024, 256, 0, stream>>>(x, emb, Wih, bih, bhh, gi_swz);
  gru_kernel<<<8, 1024, 0, stream>>>(gi_swz, whh_swz, bhh, h_seq);
  out_kernel<<<1024, 256, 0, stream>>>(h_seq, wout_swz, bout, (float*)d_out);
}

// Round 7
// 1573.640 us; speedup vs baseline: 1.1531x; 1.1295x over previous
//
#include <hip/hip_runtime.h>
#include <hip/hip_fp16.h>

// Problem constants
#define BB 128
#define SS 512
#define EE 16
#define HH 256
#define G3 768
#define VV 256

typedef _Float16 half8 __attribute__((ext_vector_type(8)));
typedef _Float16 half4_t __attribute__((ext_vector_type(4)));
typedef float f32x4 __attribute__((ext_vector_type(4)));

// ---------------------------------------------------------------------------
// P: swizzle W_hh [256][768] and W_out [256][256] (fp32, row=K, col=N) into
// fp16 MFMA B-fragment order: flat idx = ((n_tile*8 + k_tile)*64 + lane)*8 + j
//   = n*4096 + k*512 + L*8 + j
// holding W[k_tile*32 + (lane>>4)*8 + j][n_tile*16 + (lane&15)].
// ---------------------------------------------------------------------------
__global__ __launch_bounds__(256) void swizzle_weights(
    const float* __restrict__ Whh, const float* __restrict__ Wout,
    _Float16* __restrict__ whh_swz, _Float16* __restrict__ wout_swz) {
  int t = blockIdx.x * 256 + threadIdx.x;
  if (t < 48 * 8 * 64 * 8) {  // 196608 elements of W_hh
    int j = t & 7, L = (t >> 3) & 63, k = (t >> 9) & 7, n = t >> 12;
    int row = k * 32 + (L >> 4) * 8 + j;
    int col = n * 16 + (L & 15);
    whh_swz[t] = (_Float16)Whh[row * G3 + col];
  }
  if (t < 16 * 8 * 64 * 8) {  // 65536 elements of W_out
    int j = t & 7, L = (t >> 3) & 63, k = (t >> 9) & 7, n = t >> 12;
    int row = k * 32 + (L >> 4) * 8 + j;
    int col = n * 16 + (L & 15);
    wout_swz[t] = (_Float16)Wout[row * VV + col];
  }
}

// ---------------------------------------------------------------------------
// K1: gi = emb[x] @ W_ih + b_ih (+ b_hh folded for r,z gates), written fp16 in
// the swizzled per-(batch-group, t) layout K2's lanes read with 8B loads.
// 1024 blocks; each block handles 4 timesteps for one batch group, amortizing
// the 48 KB W_ih LDS staging 4x.  Static LDS = 48 + 3 + 4 KB = 55 KB.
// ---------------------------------------------------------------------------
__global__ __launch_bounds__(256) void gi_kernel(
    const int* __restrict__ x, const float* __restrict__ embed,
    const float* __restrict__ W_ih, const float* __restrict__ b_ih,
    const float* __restrict__ b_hh, _Float16* __restrict__ gi_swz) {
  int gid = blockIdx.x;          // 0..1023
  int bg = gid >> 7;             // batch group 0..7
  int t0 = (gid & 127) * 4;      // 4 timesteps per block
  int tid = threadIdx.x;

  __shared__ __align__(16) float s_wih[EE * G3];      // 48 KB
  __shared__ __align__(16) float s_bias[G3];          // 3 KB
  __shared__ __align__(16) float s_emb16[4][16][EE];  // 4 KB
  __shared__ int s_x[4][16];

  for (int i = tid; i < EE * G3; i += 256) s_wih[i] = W_ih[i];
  for (int i = tid; i < G3; i += 256)
    s_bias[i] = b_ih[i] + (i < 512 ? b_hh[i] : 0.0f);  // fold b_hh for r,z only
  if (tid < 64) {
    int tt = tid >> 4, m = tid & 15;
    s_x[tt][m] = x[(bg * 16 + m) * SS + t0 + tt];
  }
  __syncthreads();
  for (int i = tid; i < 4 * 16 * EE; i += 256) {
    int tt = i >> 8, m = (i >> 4) & 15, e = i & 15;
    s_emb16[tt][m][e] = embed[s_x[tt][m] * EE + e];
  }
  __syncthreads();

  for (int cch = 0; cch < 3; cch++) {
    int gc = cch * 256 + tid;  // gate column
    float w[EE];
#pragma unroll
    for (int e = 0; e < EE; e++) w[e] = s_wih[e * G3 + gc];
    float bias = s_bias[gc];
    int wi = (gc >> 4) & 15, cc = gc & 15;
    int tilebase = (cch * 16 + wi) * 64;
    for (int tt = 0; tt < 4; tt++) {
      size_t gbase = (size_t)(bg * 512 + t0 + tt) * 12288;
#pragma unroll
      for (int mq = 0; mq < 4; mq++) {
        half4_t v;
#pragma unroll
        for (int r = 0; r < 4; r++) {
          int m = mq * 4 + r;
          float acc = bias;
#pragma unroll
          for (int e = 0; e < EE; e++) acc += s_emb16[tt][m][e] * w[e];
          v[r] = (_Float16)acc;
        }
        *(half4_t*)(gi_swz + gbase + (size_t)((tilebase + mq * 16 + cc) * 4)) = v;
      }
    }
  }
}

// ---------------------------------------------------------------------------
// K2: GRU recurrence. 8 blocks x 1024 threads (16 waves); block bg owns batch
// rows [bg*16, bg*16+16). Wave w owns h-columns [w*16, w*16+16): one N-tile
// per gate, so all of W_hh lives in VGPRs (3x8 half8 = 96 regs/lane).
// amdgpu_waves_per_eu(4,4): pins the backend to exactly 4 waves/EU ->
// 128-VGPR budget. R5/R6 (__launch_bounds__ min-waves only) let the
// occupancy heuristic pick 8 waves/EU -> 64 VGPRs -> the 96-reg weight
// arrays spilled and were reloaded every step (VGPR_Count=64, per-CU
// VALUBusy 77% / MfmaUtil 20%, 7455 cy/step vs ~1800 model).
// Static LDS = 16.9 KB (double-buffered fp16 h tile; pad 264 halves/row).
// ---------------------------------------------------------------------------
__global__ void __launch_bounds__(1024)
__attribute__((amdgpu_waves_per_eu(4, 4)))
gru_kernel(
    const _Float16* __restrict__ gi_swz, const _Float16* __restrict__ whh_swz,
    const float* __restrict__ b_hh, _Float16* __restrict__ h_seq) {
  int bg = blockIdx.x;  // 0..7
  int tid = threadIdx.x;
  int w = tid >> 6, L = tid & 63;
  int q = L >> 4, c = L & 15;

  __shared__ __align__(16) _Float16 s_h[2][16][264];  // 16.9 KB

  // All three B fragments for this wave's column tile, in registers (96 VGPR).
  half8 wR[8], wZ[8], wN[8];
#pragma unroll
  for (int k = 0; k < 8; k++) {
    wR[k] = *(const half8*)(whh_swz + (((size_t)((0 * 16 + w) * 8 + k) * 64 + L) * 8));
    wZ[k] = *(const half8*)(whh_swz + (((size_t)((1 * 16 + w) * 8 + k) * 64 + L) * 8));
    wN[k] = *(const half8*)(whh_swz + (((size_t)((2 * 16 + w) * 8 + k) * 64 + L) * 8));
  }
  // n-gate hidden bias (multiplied by r inside the step)
  float bhn = b_hh[512 + w * 16 + c];

  // zero both h buffers (h0 = 0): 8448 halves = 4224 uints
  for (int idx = tid; idx < (2 * 16 * 264) / 2; idx += 1024)
    ((unsigned int*)s_h)[idx] = 0u;
  __syncthreads();

  int col = w * 16 + c;
  // h_seq flat offset for (batch row bg*16 + q*4, t=0, col); advance by HH/step
  unsigned hoff = (unsigned)(bg * 16 + q * 4) * (SS * HH) + (unsigned)col;
  // gi base offset for this lane (advance by 12288/step)
  unsigned gioff = (unsigned)(bg * 512) * 12288u + (unsigned)((w * 64 + L) * 4);

  int cur = 0;
#pragma unroll 1
  for (int t = 0; t < SS; t++) {
    // gate-input loads (global; issued early, consumed in epilogue)
    half4_t giR = *(const half4_t*)(gi_swz + gioff);
    half4_t giZ = *(const half4_t*)(gi_swz + gioff + 4096u);
    half4_t giN = *(const half4_t*)(gi_swz + gioff + 8192u);

    const _Float16* hsrc = &s_h[cur][0][0];
    // lane's own h_{t-1} values (C-layout positions), fp16
    half4_t hp;
#pragma unroll
    for (int r = 0; r < 4; r++) hp[r] = hsrc[(q * 4 + r) * 264 + col];

    f32x4 aR = {0.f, 0.f, 0.f, 0.f}, aZ = aR, aN = aR;
#pragma unroll
    for (int k = 0; k < 8; k++) {
      half8 av = *(const half8*)(hsrc + c * 264 + k * 32 + q * 8);  // A[m=c][k*32+q*8+j]
      aR = __builtin_amdgcn_mfma_f32_16x16x32_f16(av, wR[k], aR, 0, 0, 0);
      aZ = __builtin_amdgcn_mfma_f32_16x16x32_f16(av, wZ[k], aZ, 0, 0, 0);
      aN = __builtin_amdgcn_mfma_f32_16x16x32_f16(av, wN[k], aN, 0, 0, 0);
    }

    _Float16* hdst = &s_h[cur ^ 1][0][0];
#pragma unroll
    for (int r = 0; r < 4; r++) {
      int m = q * 4 + r;  // C/D row = (lane>>4)*4 + reg
      float rg = aR[r] + (float)giR[r];
      rg = 1.f / (1.f + __expf(-rg));
      float zg = aZ[r] + (float)giZ[r];
      zg = 1.f / (1.f + __expf(-zg));
      float ng = (float)giN[r] + rg * (aN[r] + bhn);
      ng = 2.f / (1.f + __expf(-2.f * ng)) - 1.f;  // tanh
      float hn = (1.f - zg) * ng + zg * (float)hp[r];
      hdst[m * 264 + col] = (_Float16)hn;
      h_seq[(size_t)hoff + (unsigned)r * (SS * HH)] = (_Float16)hn;
    }
    __syncthreads();
    cur ^= 1;
    hoff += HH;
    gioff += 12288u;
  }
}

// ---------------------------------------------------------------------------
// K3: out = h_seq @ W_out + b_out via fp16 MFMA. 1024 blocks x 256 threads;
// block handles 64 bt-rows (wave w -> rows w*16..+16), full N=256 (16 tiles).
// Static LDS = 33 KB.  Output written fp32.
// ---------------------------------------------------------------------------
__global__ __launch_bounds__(256) void out_kernel(
    const _Float16* __restrict__ h_seq, const _Float16* __restrict__ wout_swz,
    const float* __restrict__ b_out, float* __restrict__ out) {
  int blk = blockIdx.x;
  int tid = threadIdx.x;
  int w = tid >> 6, L = tid & 63, q = L >> 4, c = L & 15;

  __shared__ __align__(16) _Float16 s_a[64 * 264];  // 33 KB

  const _Float16* src = h_seq + (size_t)blk * 64 * 256;
  for (int idx = tid; idx < (64 * 256) / 8; idx += 256) {
    int row = idx >> 5, kk = (idx & 31) * 8;
    *(half8*)(s_a + row * 264 + kk) = *(const half8*)(src + row * 256 + kk);
  }
  __syncthreads();

  half8 a[8];
#pragma unroll
  for (int k = 0; k < 8; k++)
    a[k] = *(const half8*)(s_a + (w * 16 + c) * 264 + k * 32 + q * 8);

  f32x4 acc[16];
#pragma unroll
  for (int n = 0; n < 16; n++) {
    f32x4 z = {0.f, 0.f, 0.f, 0.f};
    acc[n] = z;
#pragma unroll
    for (int k = 0; k < 8; k++) {
      half8 b = *(const half8*)(wout_swz + ((size_t)(n * 8 + k) * 64 + L) * 8);
      acc[n] = __builtin_amdgcn_mfma_f32_16x16x32_f16(a[k], b, acc[n], 0, 0, 0);
    }
  }
#pragma unroll
  for (int n = 0; n < 16; n++) {
    int v = n * 16 + c;
    float bo = b_out[v];
#pragma unroll
    for (int r = 0; r < 4; r++) {
      int bt = blk * 64 + w * 16 + q * 4 + r;
      out[(size_t)bt * 256 + v] = acc[n][r] + bo;
    }
  }
}

// ---------------------------------------------------------------------------
extern "C" void kernel_launch(void* const* d_in, const int* in_sizes, int n_in,
                              void* d_out, int out_size, void* d_ws, size_t ws_size,
                              hipStream_t stream) {
  const int*   x    = (const int*)d_in[0];
  const float* emb  = (const float*)d_in[1];
  const float* Wih  = (const float*)d_in[2];
  const float* bih  = (const float*)d_in[3];
  const float* Whh  = (const float*)d_in[4];
  const float* bhh  = (const float*)d_in[5];
  const float* Wout = (const float*)d_in[6];
  const float* bout = (const float*)d_in[7];

  char* ws = (char*)d_ws;
  // ws layout (134,742,016 B total):
  //   gi_swz   : 128*512*768 fp16 = 100,663,296 B
  //   whh_swz  : 196608 fp16      =     393,216 B
  //   wout_swz : 65536 fp16       =     131,072 B
  //   h_seq    : 128*512*256 fp16 =  33,554,432 B
  _Float16* gi_swz   = (_Float16*)(ws);
  _Float16* whh_swz  = (_Float16*)(ws + 100663296);
  _Float16* wout_swz = (_Float16*)(ws + 100663296 + 393216);
  _Float16* h_seq    = (_Float16*)(ws + 100663296 + 393216 + 131072);

  swizzle_weights<<<768, 256, 0, stream>>>(Whh, Wout, whh_swz, wout_swz);
  gi_kernel<<<1024, 256, 0, stream>>>(x, emb, Wih, bih, bhh, gi_swz);
  gru_kernel<<<8, 1024, 0, stream>>>(gi_swz, whh_swz, bhh, h_seq);
  out_kernel<<<1024, 256, 0, stream>>>(h_seq, wout_swz, bout, (float*)d_out);
}